// Round 2
// baseline (305.298 us; speedup 1.0000x reference)
//
#include <hip/hip_runtime.h>
#include <math.h>

// Problem dims (fixed by the reference)
#define SEQ   512
#define BATCH 1024
#define NFEAT 128
#define HID   20
#define NCLS  10

// ---------------------------------------------------------------------------
// Kernel A: xp[t][b][h] = dot(x[t][b][:], W_ih[h][:]) + b_ih[h] + b_hh[h]
// 4 rows per thread: amortizes the wave-uniform W_ih SGPR loads 4x
// (320 FMA per 20 s_load_dwordx4) so the kernel becomes memory-streaming
// bound instead of lgkmcnt-stall bound. Explicit double-buffered x prefetch.
// ---------------------------------------------------------------------------
#define RPT 4   // rows per thread

__global__ __launch_bounds__(256) void k_input_proj(
    const float* __restrict__ x, const float* __restrict__ W_ih,
    const float* __restrict__ b_ih, const float* __restrict__ b_hh,
    float* __restrict__ xp)
{
  const int wid  = (blockIdx.x * 256 + threadIdx.x) >> 6;  // global wave id
  const int lane = threadIdx.x & 63;
  const int row0 = wid * (64 * RPT) + lane;  // rows: row0 + k*64

  const float4* __restrict__ W4 = reinterpret_cast<const float4*>(W_ih);
  const float4* __restrict__ xr[RPT];
#pragma unroll
  for (int k = 0; k < RPT; ++k)
    xr[k] = reinterpret_cast<const float4*>(x) + (size_t)(row0 + k * 64) * (NFEAT / 4);

  float acc[RPT][HID];
#pragma unroll
  for (int k = 0; k < RPT; ++k)
#pragma unroll
    for (int h = 0; h < HID; ++h) acc[k][h] = 0.0f;

  float4 bufA[RPT], bufB[RPT];
#pragma unroll
  for (int k = 0; k < RPT; ++k) bufA[k] = xr[k][0];

#define DO_CHUNK(BUF, C)                                                       \
  {                                                                            \
    _Pragma("unroll")                                                          \
    for (int h = 0; h < HID; ++h) {                                            \
      const float4 wv = W4[h * (NFEAT / 4) + (C)];                             \
      _Pragma("unroll")                                                        \
      for (int k = 0; k < RPT; ++k) {                                          \
        float a = acc[k][h];                                                   \
        a = fmaf(BUF[k].x, wv.x, a);                                           \
        a = fmaf(BUF[k].y, wv.y, a);                                           \
        a = fmaf(BUF[k].z, wv.z, a);                                           \
        a = fmaf(BUF[k].w, wv.w, a);                                           \
        acc[k][h] = a;                                                         \
      }                                                                        \
    }                                                                          \
  }

  for (int c = 0; c < NFEAT / 4; c += 2) {
#pragma unroll
    for (int k = 0; k < RPT; ++k) bufB[k] = xr[k][c + 1];
    DO_CHUNK(bufA, c);
    if (c + 2 < NFEAT / 4) {
#pragma unroll
      for (int k = 0; k < RPT; ++k) bufA[k] = xr[k][c + 2];
    }
    DO_CHUNK(bufB, c + 1);
  }
#undef DO_CHUNK

  // epilogue: add biases (wave-uniform s_loads), float4 stores
#pragma unroll
  for (int k = 0; k < RPT; ++k) {
    float* __restrict__ op = xp + (size_t)(row0 + k * 64) * HID;
#pragma unroll
    for (int h = 0; h < HID; h += 4) {
      float4 o;
      o.x = acc[k][h + 0] + b_ih[h + 0] + b_hh[h + 0];
      o.y = acc[k][h + 1] + b_ih[h + 1] + b_hh[h + 1];
      o.z = acc[k][h + 2] + b_ih[h + 2] + b_hh[h + 2];
      o.w = acc[k][h + 3] + b_ih[h + 3] + b_hh[h + 3];
      *reinterpret_cast<float4*>(op + h) = o;
    }
  }
}

// ---------------------------------------------------------------------------
// Kernel B: 512-step recurrence + final FC. One batch per WAVE.
// Lane j owns h[j] and W_hh row j in VGPRs. The h broadcast each step is
// 20x v_readlane into SGPRs (SALU pipe, no LDS latency); the SGPR value
// feeds v_fmac directly (1 SGPR operand per VALU is legal). Branch-free
// tanh: clamp, e=exp(2s), (e-1)*rcp(e+1). No LDS, no barriers.
// Per-step critical path ~110 cyc vs ~280 for the LDS round-trip version.
// ---------------------------------------------------------------------------
#define PF 8    // xp prefetch depth (steps)

__device__ __forceinline__ float tanh_fast(float s) {
  s = fminf(fmaxf(s, -9.0f), 9.0f);        // v_med3; tanh(9) == 1.0f in fp32
  const float e = __expf(2.0f * s);        // native v_exp_f32 path
  return (e - 1.0f) * __builtin_amdgcn_rcpf(e + 1.0f);
}

__global__ __launch_bounds__(256) void k_rnn_scan(
    const float* __restrict__ xp, const float* __restrict__ W_hh,
    const float* __restrict__ W_fc, const float* __restrict__ b_fc,
    float* __restrict__ out)
{
  const int lane = threadIdx.x & 63;
  const int wv   = threadIdx.x >> 6;
  const int b    = blockIdx.x * 4 + wv;      // batch handled by this wave
  const int j    = lane < HID ? lane : HID - 1;   // clamp (lanes 20..63 mirror 19)

  // W_hh row j -> 20 VGPRs (j*80 bytes: 16B aligned)
  float w[HID];
  {
    const float4* wr = reinterpret_cast<const float4*>(W_hh + j * HID);
#pragma unroll
    for (int q = 0; q < HID / 4; ++q) {
      const float4 v = wr[q];
      w[q * 4 + 0] = v.x; w[q * 4 + 1] = v.y;
      w[q * 4 + 2] = v.z; w[q * 4 + 3] = v.w;
    }
  }

  const float* __restrict__ xl = xp + b * HID + j;
  const int STRIDE = BATCH * HID;

  float hn = 0.0f;   // lane j holds h[j]

#define RL(K) __uint_as_float(__builtin_amdgcn_readlane(__float_as_uint(hn), (K)))
#define STEP(XV)                                                               \
  {                                                                            \
    float a0 = (XV), a1 = 0.0f, a2 = 0.0f, a3 = 0.0f;                          \
    a0 = fmaf(w[0],  RL(0),  a0); a1 = fmaf(w[1],  RL(1),  a1);                \
    a2 = fmaf(w[2],  RL(2),  a2); a3 = fmaf(w[3],  RL(3),  a3);                \
    a0 = fmaf(w[4],  RL(4),  a0); a1 = fmaf(w[5],  RL(5),  a1);                \
    a2 = fmaf(w[6],  RL(6),  a2); a3 = fmaf(w[7],  RL(7),  a3);                \
    a0 = fmaf(w[8],  RL(8),  a0); a1 = fmaf(w[9],  RL(9),  a1);                \
    a2 = fmaf(w[10], RL(10), a2); a3 = fmaf(w[11], RL(11), a3);                \
    a0 = fmaf(w[12], RL(12), a0); a1 = fmaf(w[13], RL(13), a1);                \
    a2 = fmaf(w[14], RL(14), a2); a3 = fmaf(w[15], RL(15), a3);                \
    a0 = fmaf(w[16], RL(16), a0); a1 = fmaf(w[17], RL(17), a1);                \
    a2 = fmaf(w[18], RL(18), a2); a3 = fmaf(w[19], RL(19), a3);                \
    const float s_ = (a0 + a1) + (a2 + a3);                                    \
    hn = tanh_fast(s_);                                                        \
  }

  float bufA[PF], bufB[PF];
#pragma unroll
  for (int i = 0; i < PF; ++i) bufA[i] = xl[i * STRIDE];

  for (int c = 0; c < SEQ / PF; c += 2) {
#pragma unroll
    for (int i = 0; i < PF; ++i) bufB[i] = xl[((c + 1) * PF + i) * STRIDE];
#pragma unroll
    for (int i = 0; i < PF; ++i) STEP(bufA[i]);
    if (c + 2 < SEQ / PF) {
#pragma unroll
      for (int i = 0; i < PF; ++i) bufA[i] = xl[((c + 2) * PF + i) * STRIDE];
    }
#pragma unroll
    for (int i = 0; i < PF; ++i) STEP(bufB[i]);
  }

  // FC epilogue: out[b][c] = b_fc[c] + sum_k W_fc[c][k] * h[k]
  {
    const int c = lane < NCLS ? lane : NCLS - 1;
    float acc = b_fc[c];
#pragma unroll
    for (int k = 0; k < HID; ++k)
      acc = fmaf(W_fc[c * HID + k], RL(k), acc);
    if (lane < NCLS) out[b * NCLS + lane] = acc;
  }
#undef STEP
#undef RL
}

// ---------------------------------------------------------------------------
extern "C" void kernel_launch(void* const* d_in, const int* in_sizes, int n_in,
                              void* d_out, int out_size, void* d_ws, size_t ws_size,
                              hipStream_t stream) {
  const float* x    = (const float*)d_in[0];
  const float* W_ih = (const float*)d_in[1];
  const float* W_hh = (const float*)d_in[2];
  const float* b_ih = (const float*)d_in[3];
  const float* b_hh = (const float*)d_in[4];
  const float* W_fc = (const float*)d_in[5];
  const float* b_fc = (const float*)d_in[6];
  float* out = (float*)d_out;

  float* xp = (float*)d_ws;  // SEQ*BATCH*HID floats = 41.9 MB

  const int nthreads = (SEQ * BATCH) / RPT;           // 131072
  k_input_proj<<<nthreads / 256, 256, 0, stream>>>(x, W_ih, b_ih, b_hh, xp);

  k_rnn_scan<<<BATCH / 4, 256, 0, stream>>>(xp, W_hh, W_fc, b_fc, out);
}

// Round 3
// 275.129 us; speedup vs baseline: 1.1097x; 1.1097x over previous
//
#include <hip/hip_runtime.h>
#include <math.h>

// Problem dims (fixed by the reference)
#define SEQ   512
#define BATCH 1024
#define NFEAT 128
#define HID   20
#define NCLS  10

// ---------------------------------------------------------------------------
// Kernel A: xp[t][b][h] = dot(x[t][b][:], W_ih[h][:]) + b_ih[h] + b_hh[h]
// Lane decomposition: lane = (g, q), g = lane>>2 (16 row-groups), q = lane&3
// (h-split: lane owns h = 5q..5q+4). Each group handles 4 rows (k-streams
// rs + k*16 + g). The 4 q-lanes read the SAME x address (HW broadcast), so
// wave footprint = 64 consecutive rows, each 64B line fully consumed within
// 4 iterations (~4KB live in L1) -> no over-fetch (R2 bug fixed).
// W_ih (10 KB) is read via per-lane VECTOR loads -> L1-resident broadcast,
// vmcnt-counted and pipelined (no SMEM lgkmcnt(0) drain that capped R1).
// Per lane-iter: 80 FMA, 5 W-loads (float4), 4 x-loads (float4).
// ---------------------------------------------------------------------------
__global__ __launch_bounds__(256) void k_input_proj(
    const float* __restrict__ x, const float* __restrict__ W_ih,
    const float* __restrict__ b_ih, const float* __restrict__ b_hh,
    float* __restrict__ xp)
{
  const int lane = threadIdx.x & 63;
  const int wv   = threadIdx.x >> 6;
  const int g    = lane >> 2;   // row within 16-row panel
  const int q    = lane & 3;    // h-group: h = 5q + hh
  const int rs   = (blockIdx.x * 4 + wv) * 64;

  const float4* __restrict__ xr[4];
#pragma unroll
  for (int k = 0; k < 4; ++k)
    xr[k] = reinterpret_cast<const float4*>(x + (size_t)(rs + k * 16 + g) * NFEAT);

  const float4* __restrict__ wr[5];
#pragma unroll
  for (int hh = 0; hh < 5; ++hh)
    wr[hh] = reinterpret_cast<const float4*>(W_ih + (5 * q + hh) * NFEAT);

  float acc[4][5];
#pragma unroll
  for (int k = 0; k < 4; ++k)
#pragma unroll
    for (int hh = 0; hh < 5; ++hh) acc[k][hh] = 0.0f;

  float4 xa[4], xb[4];
#pragma unroll
  for (int k = 0; k < 4; ++k) xa[k] = xr[k][0];

#define DO_CHUNK(XBUF, C)                                                      \
  {                                                                            \
    _Pragma("unroll")                                                          \
    for (int hh = 0; hh < 5; ++hh) {                                           \
      const float4 wv4 = wr[hh][(C)];                                          \
      _Pragma("unroll")                                                        \
      for (int k = 0; k < 4; ++k) {                                            \
        float a = acc[k][hh];                                                  \
        a = fmaf(XBUF[k].x, wv4.x, a);                                         \
        a = fmaf(XBUF[k].y, wv4.y, a);                                         \
        a = fmaf(XBUF[k].z, wv4.z, a);                                         \
        a = fmaf(XBUF[k].w, wv4.w, a);                                         \
        acc[k][hh] = a;                                                        \
      }                                                                        \
    }                                                                          \
  }

  for (int c = 0; c < NFEAT / 4; c += 2) {
#pragma unroll
    for (int k = 0; k < 4; ++k) xb[k] = xr[k][c + 1];
    DO_CHUNK(xa, c);
    if (c + 2 < NFEAT / 4) {
#pragma unroll
      for (int k = 0; k < 4; ++k) xa[k] = xr[k][c + 2];
    }
    DO_CHUNK(xb, c + 1);
  }
#undef DO_CHUNK

  // epilogue: bias + store. Lane's h's are 5q+hh.
  float bias[5];
#pragma unroll
  for (int hh = 0; hh < 5; ++hh)
    bias[hh] = b_ih[5 * q + hh] + b_hh[5 * q + hh];

#pragma unroll
  for (int k = 0; k < 4; ++k) {
    float* __restrict__ op = xp + (size_t)(rs + k * 16 + g) * HID + 5 * q;
#pragma unroll
    for (int hh = 0; hh < 5; ++hh)
      op[hh] = acc[k][hh] + bias[hh];
  }
}

// ---------------------------------------------------------------------------
// Kernel B: 512-step recurrence + final FC (R1's proven LDS-exchange
// structure: 1 wave/block, 3 batches/wave, lane j owns h[j] + W_hh row j in
// VGPRs; h exchanged via 1 ds_write + 5 conflict-free broadcast ds_read_b128
// per step, no s_barrier needed in a single-wave block).
// Change vs R1: branch-free tanh (med3 clamp -> v_exp -> rcp) replaces the
// branchy libm tanhf on the serial chain (~-40 cyc/step).
// ---------------------------------------------------------------------------
#define BPW 3   // batches per wave
#define PF  8   // xp prefetch chunk (steps)

__device__ __forceinline__ float tanh_fast(float s) {
  s = fminf(fmaxf(s, -9.0f), 9.0f);        // v_med3; tanh(9)==1.0f in fp32
  const float e = __expf(2.0f * s);        // v_exp_f32 path
  return (e - 1.0f) * __builtin_amdgcn_rcpf(e + 1.0f);
}

__global__ __launch_bounds__(64) void k_rnn_scan(
    const float* __restrict__ xp, const float* __restrict__ W_hh,
    const float* __restrict__ W_fc, const float* __restrict__ b_fc,
    float* __restrict__ out)
{
  __shared__ __align__(16) float hsh[4][HID];  // [group][h]
  const int lane = threadIdx.x;
  const int g = lane / HID;        // 0..3
  const int j = lane - g * HID;    // 0..19
  const int b = blockIdx.x * BPW + g;
  const bool valid = (g < BPW) && (b < BATCH);
  const int beff = valid ? b : 0;

  // W_hh row j -> registers
  float w[HID];
  {
    const float4* wr = reinterpret_cast<const float4*>(W_hh + j * HID);
#pragma unroll
    for (int qq = 0; qq < HID / 4; ++qq) {
      const float4 v = wr[qq];
      w[qq * 4 + 0] = v.x; w[qq * 4 + 1] = v.y;
      w[qq * 4 + 2] = v.z; w[qq * 4 + 3] = v.w;
    }
  }

  hsh[g][j] = 0.0f;  // h0 = 0 (note: hsh[3][4..19] stays uninit; g==3 lanes
                     // are invalid and their results are never read; tanh's
                     // clamp keeps any garbage finite)
  __builtin_amdgcn_wave_barrier();

  const float* __restrict__ xl = xp + beff * HID + j;
  const int STRIDE = BATCH * HID;
  const float4* __restrict__ hp = reinterpret_cast<const float4*>(&hsh[g][0]);

  float bufA[PF], bufB[PF];

#define STEPF(XV)                                                              \
  {                                                                            \
    float4 h0 = hp[0], h1 = hp[1], h2 = hp[2], h3 = hp[3], h4 = hp[4];         \
    float a0 = fmaf(w[3], h0.w, fmaf(w[2], h0.z, fmaf(w[1], h0.y, fmaf(w[0], h0.x, (XV))))); \
    float a1 = fmaf(w[7], h1.w, fmaf(w[6], h1.z, fmaf(w[5], h1.y, w[4] * h1.x)));            \
    float a2 = fmaf(w[11], h2.w, fmaf(w[10], h2.z, fmaf(w[9], h2.y, w[8] * h2.x)));          \
    float a3 = fmaf(w[15], h3.w, fmaf(w[14], h3.z, fmaf(w[13], h3.y, w[12] * h3.x)));        \
    float a4 = fmaf(w[19], h4.w, fmaf(w[18], h4.z, fmaf(w[17], h4.y, w[16] * h4.x)));        \
    float s_ = (a0 + a1) + ((a2 + a3) + a4);                                   \
    float hn = tanh_fast(s_);                                                  \
    __builtin_amdgcn_wave_barrier();                                           \
    hsh[g][j] = hn;                                                            \
    __builtin_amdgcn_wave_barrier();                                           \
  }

  // prologue: preload chunk 0
#pragma unroll
  for (int i = 0; i < PF; ++i) bufA[i] = xl[i * STRIDE];

  for (int c = 0; c < SEQ / PF; c += 2) {
#pragma unroll
    for (int i = 0; i < PF; ++i) bufB[i] = xl[((c + 1) * PF + i) * STRIDE];
#pragma unroll
    for (int i = 0; i < PF; ++i) STEPF(bufA[i]);
    if (c + 2 < SEQ / PF) {
#pragma unroll
      for (int i = 0; i < PF; ++i) bufA[i] = xl[((c + 2) * PF + i) * STRIDE];
    }
#pragma unroll
    for (int i = 0; i < PF; ++i) STEPF(bufB[i]);
  }

  // FC epilogue: out[b][c] = b_fc[c] + sum_k W_fc[c][k] * h_final[k]
  if (valid && j < NCLS) {
    float acc = b_fc[j];
#pragma unroll
    for (int k = 0; k < HID; ++k)
      acc = fmaf(W_fc[j * HID + k], hsh[g][k], acc);
    out[b * NCLS + j] = acc;
  }
#undef STEPF
}

// ---------------------------------------------------------------------------
extern "C" void kernel_launch(void* const* d_in, const int* in_sizes, int n_in,
                              void* d_out, int out_size, void* d_ws, size_t ws_size,
                              hipStream_t stream) {
  const float* x    = (const float*)d_in[0];
  const float* W_ih = (const float*)d_in[1];
  const float* W_hh = (const float*)d_in[2];
  const float* b_ih = (const float*)d_in[3];
  const float* b_hh = (const float*)d_in[4];
  const float* W_fc = (const float*)d_in[5];
  const float* b_fc = (const float*)d_in[6];
  float* out = (float*)d_out;

  float* xp = (float*)d_ws;  // SEQ*BATCH*HID floats = 41.9 MB

  // 2048 blocks x 4 waves x 64 rows/wave = 524288 rows
  k_input_proj<<<(SEQ * BATCH) / 256, 256, 0, stream>>>(x, W_ih, b_ih, b_hh, xp);

  const int nblk = (BATCH + BPW - 1) / BPW;  // 342
  k_rnn_scan<<<nblk, 64, 0, stream>>>(xp, W_hh, W_fc, b_fc, out);
}

// Round 4
// 145.300 us; speedup vs baseline: 2.1011x; 1.8935x over previous
//
#include <hip/hip_runtime.h>
#include <math.h>

// Problem dims (fixed by the reference)
#define SEQ   512
#define BATCH 1024
#define NFEAT 128
#define HID   20
#define NCLS  10

typedef __attribute__((ext_vector_type(8))) short short8v;  // 8 bf16 (4 VGPR)
typedef __attribute__((ext_vector_type(4))) float f32x4;    // MFMA 16x16 acc
typedef __attribute__((ext_vector_type(4))) unsigned int u32x4;

__device__ __forceinline__ float truncbf(float f) {
  return __uint_as_float(__float_as_uint(f) & 0xffff0000u);
}
// pack bf16(a) (truncated) into low half, bf16(b) into high half
__device__ __forceinline__ unsigned packhi2(float a, float b) {
  return (__float_as_uint(a) >> 16) | (__float_as_uint(b) & 0xffff0000u);
}
__device__ __forceinline__ short8v mk8(unsigned a, unsigned b, unsigned c, unsigned d) {
  u32x4 u; u[0] = a; u[1] = b; u[2] = c; u[3] = d;
  return __builtin_bit_cast(short8v, u);
}
// fp32 octet -> (hi bf16x8, lo bf16x8); x == hi + lo to ~2^-17 rel
__device__ __forceinline__ void cvt_hilo(float4 ca, float4 cb, short8v& hi, short8v& lo) {
  hi = mk8(packhi2(ca.x, ca.y), packhi2(ca.z, ca.w),
           packhi2(cb.x, cb.y), packhi2(cb.z, cb.w));
  const float l0 = ca.x - truncbf(ca.x);
  const float l1 = ca.y - truncbf(ca.y);
  const float l2 = ca.z - truncbf(ca.z);
  const float l3 = ca.w - truncbf(ca.w);
  const float l4 = cb.x - truncbf(cb.x);
  const float l5 = cb.y - truncbf(cb.y);
  const float l6 = cb.z - truncbf(cb.z);
  const float l7 = cb.w - truncbf(cb.w);
  lo = mk8(packhi2(l0, l1), packhi2(l2, l3), packhi2(l4, l5), packhi2(l6, l7));
}

// ---------------------------------------------------------------------------
// Kernel A (MFMA): xp = x @ W_ih^T + b_ih + b_hh as a [524288 x 128]x[128 x 20]
// GEMM on the matrix cores, bf16x2-split for fp32-grade accuracy.
// W fragments (hi+lo, N padded to 32) are RESIDENT in 64 VGPRs -> zero
// per-iteration W traffic; the kernel is a pure x-streaming pipeline.
// Per wave-tile (16 rows): 8 float4 loads (ping-pong prefetched), ~100 VALU
// pack/convert, 24 mfma_16x16x32_bf16. Memory-bound at ~6 TB/s target.
// Fragment layouts (verified m89/m92): A row=lane&15, k=(lane>>4)*8+i;
// B col=lane&15 (W_ih is row-major [n][k] = B^T); C col=lane&15,
// row=(lane>>4)*4+reg.
// ---------------------------------------------------------------------------
#define TPW 4   // 16-row tiles per wave

__global__ __launch_bounds__(256, 4) void k_input_proj(
    const float* __restrict__ x, const float* __restrict__ W_ih,
    const float* __restrict__ b_ih, const float* __restrict__ b_hh,
    float* __restrict__ xp)
{
  const int lane = threadIdx.x & 63;
  const int gw   = blockIdx.x * 4 + (threadIdx.x >> 6);  // global wave id
  const int rr   = lane & 15;   // A-row within tile / C-col
  const int kq   = lane >> 4;   // k-group (0..3), 8 k's each

  // ---- W -> resident B fragments (hi/lo, 2 n-tiles x 4 k-chunks)
  short8v Bhi[2][4], Blo[2][4];
#pragma unroll
  for (int nt = 0; nt < 2; ++nt) {
    const int n = nt * 16 + rr;
    const bool v = (n < HID);
#pragma unroll
    for (int k = 0; k < 4; ++k) {
      float4 wa = {0.f, 0.f, 0.f, 0.f}, wb = {0.f, 0.f, 0.f, 0.f};
      if (v) {
        const float* wp = W_ih + n * NFEAT + k * 32 + kq * 8;
        wa = *reinterpret_cast<const float4*>(wp);
        wb = *reinterpret_cast<const float4*>(wp + 4);
      }
      cvt_hilo(wa, wb, Bhi[nt][k], Blo[nt][k]);
    }
  }

  const float badd0 = b_ih[rr] + b_hh[rr];
  const int   n1    = 16 + rr;
  const float badd1 = (n1 < HID) ? (b_ih[n1] + b_hh[n1]) : 0.0f;

  const int t0 = gw * TPW;

#define LOADCHUNK(A4, B4, T, K) {                                              \
    const float* p_ = x + (size_t)(T) * (16 * NFEAT) + rr * NFEAT              \
                        + (K) * 32 + kq * 8;                                   \
    A4 = *reinterpret_cast<const float4*>(p_);                                 \
    B4 = *reinterpret_cast<const float4*>(p_ + 4); }

  float4 p0a, p0b, p1a, p1b;
  LOADCHUNK(p0a, p0b, t0, 0);

  for (int t = t0; t < t0 + TPW; ++t) {
    f32x4 acc0 = {0.f, 0.f, 0.f, 0.f};
    f32x4 acc1 = {0.f, 0.f, 0.f, 0.f};
#pragma unroll
    for (int k = 0; k < 4; ++k) {
      const bool last = (k == 3) && (t == t0 + TPW - 1);
      const int  tn   = (k == 3) ? (t + 1) : t;
      const int  kn   = (k + 1) & 3;
      if (k & 1) { if (!last) LOADCHUNK(p0a, p0b, tn, kn) }
      else       {            LOADCHUNK(p1a, p1b, tn, kn) }
      const float4 ca = (k & 1) ? p1a : p0a;
      const float4 cb = (k & 1) ? p1b : p0b;
      short8v Ahi, Alo;
      cvt_hilo(ca, cb, Ahi, Alo);
      acc0 = __builtin_amdgcn_mfma_f32_16x16x32_bf16(Ahi, Bhi[0][k], acc0, 0, 0, 0);
      acc0 = __builtin_amdgcn_mfma_f32_16x16x32_bf16(Ahi, Blo[0][k], acc0, 0, 0, 0);
      acc0 = __builtin_amdgcn_mfma_f32_16x16x32_bf16(Alo, Bhi[0][k], acc0, 0, 0, 0);
      acc1 = __builtin_amdgcn_mfma_f32_16x16x32_bf16(Ahi, Bhi[1][k], acc1, 0, 0, 0);
      acc1 = __builtin_amdgcn_mfma_f32_16x16x32_bf16(Ahi, Blo[1][k], acc1, 0, 0, 0);
      acc1 = __builtin_amdgcn_mfma_f32_16x16x32_bf16(Alo, Bhi[1][k], acc1, 0, 0, 0);
    }
    // epilogue: C(row = kq*4+reg, col = rr | 16+rr) + bias -> xp
    const int R = t * 16;
#pragma unroll
    for (int reg = 0; reg < 4; ++reg) {
      float* prow = xp + (size_t)(R + kq * 4 + reg) * HID;
      prow[rr] = acc0[reg] + badd0;
      if (n1 < HID) prow[n1] = acc1[reg] + badd1;
    }
  }
#undef LOADCHUNK
}

// ---------------------------------------------------------------------------
// Kernel B: 512-step recurrence + final FC (unchanged from R3, ~49 us:
// 1 wave/block, 3 batches/wave, lane j owns h[j] + W_hh row j in VGPRs;
// h exchanged via 1 ds_write + 5 conflict-free broadcast ds_read_b128 per
// step; branch-free tanh; no barriers needed in a single-wave block).
// ---------------------------------------------------------------------------
#define BPW 3   // batches per wave
#define PF  8   // xp prefetch chunk (steps)

__device__ __forceinline__ float tanh_fast(float s) {
  s = fminf(fmaxf(s, -9.0f), 9.0f);        // v_med3; tanh(9)==1.0f in fp32
  const float e = __expf(2.0f * s);        // v_exp_f32 path
  return (e - 1.0f) * __builtin_amdgcn_rcpf(e + 1.0f);
}

__global__ __launch_bounds__(64) void k_rnn_scan(
    const float* __restrict__ xp, const float* __restrict__ W_hh,
    const float* __restrict__ W_fc, const float* __restrict__ b_fc,
    float* __restrict__ out)
{
  __shared__ __align__(16) float hsh[4][HID];  // [group][h]
  const int lane = threadIdx.x;
  const int g = lane / HID;        // 0..3
  const int j = lane - g * HID;    // 0..19
  const int b = blockIdx.x * BPW + g;
  const bool valid = (g < BPW) && (b < BATCH);
  const int beff = valid ? b : 0;

  float w[HID];
  {
    const float4* wr = reinterpret_cast<const float4*>(W_hh + j * HID);
#pragma unroll
    for (int qq = 0; qq < HID / 4; ++qq) {
      const float4 v = wr[qq];
      w[qq * 4 + 0] = v.x; w[qq * 4 + 1] = v.y;
      w[qq * 4 + 2] = v.z; w[qq * 4 + 3] = v.w;
    }
  }

  hsh[g][j] = 0.0f;
  __builtin_amdgcn_wave_barrier();

  const float* __restrict__ xl = xp + beff * HID + j;
  const int STRIDE = BATCH * HID;
  const float4* __restrict__ hp = reinterpret_cast<const float4*>(&hsh[g][0]);

  float bufA[PF], bufB[PF];

#define STEPF(XV)                                                              \
  {                                                                            \
    float4 h0 = hp[0], h1 = hp[1], h2 = hp[2], h3 = hp[3], h4 = hp[4];         \
    float a0 = fmaf(w[3], h0.w, fmaf(w[2], h0.z, fmaf(w[1], h0.y, fmaf(w[0], h0.x, (XV))))); \
    float a1 = fmaf(w[7], h1.w, fmaf(w[6], h1.z, fmaf(w[5], h1.y, w[4] * h1.x)));            \
    float a2 = fmaf(w[11], h2.w, fmaf(w[10], h2.z, fmaf(w[9], h2.y, w[8] * h2.x)));          \
    float a3 = fmaf(w[15], h3.w, fmaf(w[14], h3.z, fmaf(w[13], h3.y, w[12] * h3.x)));        \
    float a4 = fmaf(w[19], h4.w, fmaf(w[18], h4.z, fmaf(w[17], h4.y, w[16] * h4.x)));        \
    float s_ = (a0 + a1) + ((a2 + a3) + a4);                                   \
    float hn = tanh_fast(s_);                                                  \
    __builtin_amdgcn_wave_barrier();                                           \
    hsh[g][j] = hn;                                                            \
    __builtin_amdgcn_wave_barrier();                                           \
  }

#pragma unroll
  for (int i = 0; i < PF; ++i) bufA[i] = xl[i * STRIDE];

  for (int c = 0; c < SEQ / PF; c += 2) {
#pragma unroll
    for (int i = 0; i < PF; ++i) bufB[i] = xl[((c + 1) * PF + i) * STRIDE];
#pragma unroll
    for (int i = 0; i < PF; ++i) STEPF(bufA[i]);
    if (c + 2 < SEQ / PF) {
#pragma unroll
      for (int i = 0; i < PF; ++i) bufA[i] = xl[((c + 2) * PF + i) * STRIDE];
    }
#pragma unroll
    for (int i = 0; i < PF; ++i) STEPF(bufB[i]);
  }

  if (valid && j < NCLS) {
    float acc = b_fc[j];
#pragma unroll
    for (int k = 0; k < HID; ++k)
      acc = fmaf(W_fc[j * HID + k], hsh[g][k], acc);
    out[b * NCLS + j] = acc;
  }
#undef STEPF
}

// ---------------------------------------------------------------------------
extern "C" void kernel_launch(void* const* d_in, const int* in_sizes, int n_in,
                              void* d_out, int out_size, void* d_ws, size_t ws_size,
                              hipStream_t stream) {
  const float* x    = (const float*)d_in[0];
  const float* W_ih = (const float*)d_in[1];
  const float* W_hh = (const float*)d_in[2];
  const float* b_ih = (const float*)d_in[3];
  const float* b_hh = (const float*)d_in[4];
  const float* W_fc = (const float*)d_in[5];
  const float* b_fc = (const float*)d_in[6];
  float* out = (float*)d_out;

  float* xp = (float*)d_ws;  // SEQ*BATCH*HID floats = 41.9 MB

  // 32768 16-row tiles / (2048 blocks * 4 waves) = 4 tiles per wave
  k_input_proj<<<2048, 256, 0, stream>>>(x, W_ih, b_ih, b_hh, xp);

  const int nblk = (BATCH + BPW - 1) / BPW;  // 342
  k_rnn_scan<<<nblk, 64, 0, stream>>>(xp, W_hh, W_fc, b_fc, out);
}

// Round 5
// 140.178 us; speedup vs baseline: 2.1779x; 1.0365x over previous
//
#include <hip/hip_runtime.h>
#include <math.h>

// Problem dims (fixed by the reference)
#define SEQ   512
#define BATCH 1024
#define NFEAT 128
#define HID   20
#define NCLS  10

typedef __attribute__((ext_vector_type(8))) short short8v;  // 8 bf16 (4 VGPR)
typedef __attribute__((ext_vector_type(4))) float f32x4;    // MFMA 16x16 acc
typedef __attribute__((ext_vector_type(4))) unsigned int u32x4;

__device__ __forceinline__ float truncbf(float f) {
  return __uint_as_float(__float_as_uint(f) & 0xffff0000u);
}
__device__ __forceinline__ unsigned packhi2(float a, float b) {
  return (__float_as_uint(a) >> 16) | (__float_as_uint(b) & 0xffff0000u);
}
__device__ __forceinline__ short8v mk8(unsigned a, unsigned b, unsigned c, unsigned d) {
  u32x4 u; u[0] = a; u[1] = b; u[2] = c; u[3] = d;
  return __builtin_bit_cast(short8v, u);
}
// fp32 octet -> (hi bf16x8, lo bf16x8); x == hi + lo to ~2^-17 rel
__device__ __forceinline__ void cvt_hilo(float4 ca, float4 cb, short8v& hi, short8v& lo) {
  hi = mk8(packhi2(ca.x, ca.y), packhi2(ca.z, ca.w),
           packhi2(cb.x, cb.y), packhi2(cb.z, cb.w));
  const float l0 = ca.x - truncbf(ca.x);
  const float l1 = ca.y - truncbf(ca.y);
  const float l2 = ca.z - truncbf(ca.z);
  const float l3 = ca.w - truncbf(ca.w);
  const float l4 = cb.x - truncbf(cb.x);
  const float l5 = cb.y - truncbf(cb.y);
  const float l6 = cb.z - truncbf(cb.z);
  const float l7 = cb.w - truncbf(cb.w);
  lo = mk8(packhi2(l0, l1), packhi2(l2, l3), packhi2(l4, l5), packhi2(l6, l7));
}

// ---------------------------------------------------------------------------
// Kernel A (MFMA): xp = 2*(x @ W_ih^T + b_ih + b_hh)  [the 2x pre-scale feeds
// kernel B's tanh, saving a serial multiply on the recurrence chain].
// R4 post-mortem: chunk-level ping-pong had only 2 KB/wave in flight vs
// ~900-cyc HBM latency -> ~3.3 TB/s. Fix: TILE-level double buffer (8 KB in
// flight per wave) + TPW=8 (W-fragment setup amortized over 8 tiles).
// W fragments (hi+lo bf16 split) resident in 64 VGPRs; ~150 VGPR total ->
// 2 waves/SIMD, 64 KB in flight per CU >> ~9 KB needed for 6 TB/s.
// ---------------------------------------------------------------------------
#define TPW 8   // 16-row tiles per wave

__global__ __launch_bounds__(256, 2) void k_input_proj(
    const float* __restrict__ x, const float* __restrict__ W_ih,
    const float* __restrict__ b_ih, const float* __restrict__ b_hh,
    float* __restrict__ xp)
{
  const int lane = threadIdx.x & 63;
  const int gw   = blockIdx.x * 4 + (threadIdx.x >> 6);  // global wave id
  const int rr   = lane & 15;   // A-row within tile / C-col
  const int kq   = lane >> 4;   // k-group (0..3), 8 k's each

  // ---- W -> resident B fragments (hi/lo, 2 n-tiles x 4 k-chunks)
  short8v Bhi[2][4], Blo[2][4];
#pragma unroll
  for (int nt = 0; nt < 2; ++nt) {
    const int n = nt * 16 + rr;
    const bool v = (n < HID);
#pragma unroll
    for (int k = 0; k < 4; ++k) {
      float4 wa = {0.f, 0.f, 0.f, 0.f}, wb = {0.f, 0.f, 0.f, 0.f};
      if (v) {
        const float* wp = W_ih + n * NFEAT + k * 32 + kq * 8;
        wa = *reinterpret_cast<const float4*>(wp);
        wb = *reinterpret_cast<const float4*>(wp + 4);
      }
      cvt_hilo(wa, wb, Bhi[nt][k], Blo[nt][k]);
    }
  }

  const float badd0 = b_ih[rr] + b_hh[rr];
  const int   n1    = 16 + rr;
  const float badd1 = (n1 < HID) ? (b_ih[n1] + b_hh[n1]) : 0.0f;

  const int t0 = gw * TPW;
  const float* __restrict__ xbase = x + rr * NFEAT + kq * 8;

#define LD4(P) (*reinterpret_cast<const float4*>(P))
#define LOADT(BUF, T) {                                                        \
    const float* p_ = xbase + (size_t)(T) * (16 * NFEAT);                      \
    BUF[0] = LD4(p_ +  0); BUF[1] = LD4(p_ +  4);                              \
    BUF[2] = LD4(p_ + 32); BUF[3] = LD4(p_ + 36);                              \
    BUF[4] = LD4(p_ + 64); BUF[5] = LD4(p_ + 68);                              \
    BUF[6] = LD4(p_ + 96); BUF[7] = LD4(p_ + 100); }

#define COMPSTORE(BUF, T) {                                                    \
    f32x4 acc0 = {0.f, 0.f, 0.f, 0.f};                                         \
    f32x4 acc1 = {0.f, 0.f, 0.f, 0.f};                                         \
    _Pragma("unroll")                                                          \
    for (int k = 0; k < 4; ++k) {                                              \
      short8v Ahi, Alo;                                                        \
      cvt_hilo(BUF[2 * k], BUF[2 * k + 1], Ahi, Alo);                          \
      acc0 = __builtin_amdgcn_mfma_f32_16x16x32_bf16(Ahi, Bhi[0][k], acc0, 0, 0, 0); \
      acc0 = __builtin_amdgcn_mfma_f32_16x16x32_bf16(Ahi, Blo[0][k], acc0, 0, 0, 0); \
      acc0 = __builtin_amdgcn_mfma_f32_16x16x32_bf16(Alo, Bhi[0][k], acc0, 0, 0, 0); \
      acc1 = __builtin_amdgcn_mfma_f32_16x16x32_bf16(Ahi, Bhi[1][k], acc1, 0, 0, 0); \
      acc1 = __builtin_amdgcn_mfma_f32_16x16x32_bf16(Ahi, Blo[1][k], acc1, 0, 0, 0); \
      acc1 = __builtin_amdgcn_mfma_f32_16x16x32_bf16(Alo, Bhi[1][k], acc1, 0, 0, 0); \
    }                                                                          \
    const int R = (T) * 16;                                                    \
    _Pragma("unroll")                                                          \
    for (int reg = 0; reg < 4; ++reg) {                                        \
      float* prow = xp + (size_t)(R + kq * 4 + reg) * HID;                     \
      prow[rr] = 2.0f * (acc0[reg] + badd0);                                   \
      if (n1 < HID) prow[n1] = 2.0f * (acc1[reg] + badd1);                     \
    }                                                                          \
  }

  float4 bufE[8], bufO[8];
  LOADT(bufE, t0);
#pragma unroll
  for (int tt = 0; tt < TPW; tt += 2) {
    LOADT(bufO, t0 + tt + 1);
    COMPSTORE(bufE, t0 + tt);
    if (tt + 2 < TPW) LOADT(bufE, t0 + tt + 2);
    COMPSTORE(bufO, t0 + tt + 1);
  }
#undef LOADT
#undef COMPSTORE
#undef LD4
}

// ---------------------------------------------------------------------------
// Kernel B: 512-step recurrence + final FC. 1 wave/block, 3 batches/wave,
// lane j owns h[j] + W_hh row j (pre-scaled by 2) in VGPRs; h exchanged via
// 1 ds_write + 5 conflict-free broadcast ds_read_b128 per step.
// xp arrives pre-scaled by 2 from kernel A, so the step computes s' = 2s
// directly: tanh(s) = (e^{s'}-1)/(e^{s'}+1) -- one serial mul removed from
// the 512-long dependence chain.
// ---------------------------------------------------------------------------
#define BPW 3   // batches per wave
#define PF  8   // xp prefetch chunk (steps)

__device__ __forceinline__ float tanh_scaled(float sp) {  // sp = 2*s
  sp = fminf(fmaxf(sp, -18.0f), 18.0f);    // v_med3; tanh(9)==1.0f in fp32
  const float e = __expf(sp);              // v_exp_f32 path
  return (e - 1.0f) * __builtin_amdgcn_rcpf(e + 1.0f);
}

__global__ __launch_bounds__(64) void k_rnn_scan(
    const float* __restrict__ xp, const float* __restrict__ W_hh,
    const float* __restrict__ W_fc, const float* __restrict__ b_fc,
    float* __restrict__ out)
{
  __shared__ __align__(16) float hsh[4][HID];  // [group][h]
  const int lane = threadIdx.x;
  const int g = lane / HID;        // 0..3
  const int j = lane - g * HID;    // 0..19
  const int b = blockIdx.x * BPW + g;
  const bool valid = (g < BPW) && (b < BATCH);
  const int beff = valid ? b : 0;

  // W_hh row j -> registers, pre-scaled by 2 (tanh chain shortening)
  float w[HID];
  {
    const float4* wr = reinterpret_cast<const float4*>(W_hh + j * HID);
#pragma unroll
    for (int qq = 0; qq < HID / 4; ++qq) {
      const float4 v = wr[qq];
      w[qq * 4 + 0] = 2.0f * v.x; w[qq * 4 + 1] = 2.0f * v.y;
      w[qq * 4 + 2] = 2.0f * v.z; w[qq * 4 + 3] = 2.0f * v.w;
    }
  }

  hsh[g][j] = 0.0f;
  __builtin_amdgcn_wave_barrier();

  const float* __restrict__ xl = xp + beff * HID + j;
  const int STRIDE = BATCH * HID;
  const float4* __restrict__ hp = reinterpret_cast<const float4*>(&hsh[g][0]);

  float bufA[PF], bufB[PF];

#define STEPF(XV)                                                              \
  {                                                                            \
    float4 h0 = hp[0], h1 = hp[1], h2 = hp[2], h3 = hp[3], h4 = hp[4];         \
    float a0 = fmaf(w[3], h0.w, fmaf(w[2], h0.z, fmaf(w[1], h0.y, fmaf(w[0], h0.x, (XV))))); \
    float a1 = fmaf(w[7], h1.w, fmaf(w[6], h1.z, fmaf(w[5], h1.y, w[4] * h1.x)));            \
    float a2 = fmaf(w[11], h2.w, fmaf(w[10], h2.z, fmaf(w[9], h2.y, w[8] * h2.x)));          \
    float a3 = fmaf(w[15], h3.w, fmaf(w[14], h3.z, fmaf(w[13], h3.y, w[12] * h3.x)));        \
    float a4 = fmaf(w[19], h4.w, fmaf(w[18], h4.z, fmaf(w[17], h4.y, w[16] * h4.x)));        \
    float s_ = (a0 + a1) + ((a2 + a3) + a4);                                   \
    float hn = tanh_scaled(s_);                                                \
    __builtin_amdgcn_wave_barrier();                                           \
    hsh[g][j] = hn;                                                            \
    __builtin_amdgcn_wave_barrier();                                           \
  }

#pragma unroll
  for (int i = 0; i < PF; ++i) bufA[i] = xl[i * STRIDE];

  for (int c = 0; c < SEQ / PF; c += 2) {
#pragma unroll
    for (int i = 0; i < PF; ++i) bufB[i] = xl[((c + 1) * PF + i) * STRIDE];
#pragma unroll
    for (int i = 0; i < PF; ++i) STEPF(bufA[i]);
    if (c + 2 < SEQ / PF) {
#pragma unroll
      for (int i = 0; i < PF; ++i) bufA[i] = xl[((c + 2) * PF + i) * STRIDE];
    }
#pragma unroll
    for (int i = 0; i < PF; ++i) STEPF(bufB[i]);
  }

  // FC epilogue: out[b][c] = b_fc[c] + sum_k W_fc[c][k] * h_final[k]
  if (valid && j < NCLS) {
    float acc = b_fc[j];
#pragma unroll
    for (int k = 0; k < HID; ++k)
      acc = fmaf(W_fc[j * HID + k], hsh[g][k], acc);
    out[b * NCLS + j] = acc;
  }
#undef STEPF
}

// ---------------------------------------------------------------------------
extern "C" void kernel_launch(void* const* d_in, const int* in_sizes, int n_in,
                              void* d_out, int out_size, void* d_ws, size_t ws_size,
                              hipStream_t stream) {
  const float* x    = (const float*)d_in[0];
  const float* W_ih = (const float*)d_in[1];
  const float* W_hh = (const float*)d_in[2];
  const float* b_ih = (const float*)d_in[3];
  const float* b_hh = (const float*)d_in[4];
  const float* W_fc = (const float*)d_in[5];
  const float* b_fc = (const float*)d_in[6];
  float* out = (float*)d_out;

  float* xp = (float*)d_ws;  // SEQ*BATCH*HID floats = 41.9 MB

  // 32768 16-row tiles / (1024 blocks * 4 waves) = 8 tiles per wave
  k_input_proj<<<1024, 256, 0, stream>>>(x, W_ih, b_ih, b_hh, xp);

  const int nblk = (BATCH + BPW - 1) / BPW;  // 342
  k_rnn_scan<<<nblk, 64, 0, stream>>>(xp, W_hh, W_fc, b_fc, out);
}

// Round 6
// 135.282 us; speedup vs baseline: 2.2567x; 1.0362x over previous
//
#include <hip/hip_runtime.h>
#include <math.h>

// Problem dims (fixed by the reference)
#define SEQ   512
#define BATCH 1024
#define NFEAT 128
#define HID   20
#define NCLS  10

typedef __attribute__((ext_vector_type(8))) short short8v;  // 8 bf16 (4 VGPR)
typedef __attribute__((ext_vector_type(4))) float f32x4;    // MFMA 16x16 acc
typedef __attribute__((ext_vector_type(4))) unsigned int u32x4;

__device__ __forceinline__ float truncbf(float f) {
  return __uint_as_float(__float_as_uint(f) & 0xffff0000u);
}
__device__ __forceinline__ unsigned packhi2(float a, float b) {
  return (__float_as_uint(a) >> 16) | (__float_as_uint(b) & 0xffff0000u);
}
__device__ __forceinline__ short8v mk8(unsigned a, unsigned b, unsigned c, unsigned d) {
  u32x4 u; u[0] = a; u[1] = b; u[2] = c; u[3] = d;
  return __builtin_bit_cast(short8v, u);
}
// fp32 octet -> (hi bf16x8, lo bf16x8); x == hi + lo to ~2^-17 rel
__device__ __forceinline__ void cvt_hilo(float4 ca, float4 cb, short8v& hi, short8v& lo) {
  hi = mk8(packhi2(ca.x, ca.y), packhi2(ca.z, ca.w),
           packhi2(cb.x, cb.y), packhi2(cb.z, cb.w));
  const float l0 = ca.x - truncbf(ca.x);
  const float l1 = ca.y - truncbf(ca.y);
  const float l2 = ca.z - truncbf(ca.z);
  const float l3 = ca.w - truncbf(ca.w);
  const float l4 = cb.x - truncbf(cb.x);
  const float l5 = cb.y - truncbf(cb.y);
  const float l6 = cb.z - truncbf(cb.z);
  const float l7 = cb.w - truncbf(cb.w);
  lo = mk8(packhi2(l0, l1), packhi2(l2, l3), packhi2(l4, l5), packhi2(l6, l7));
}

// ---------------------------------------------------------------------------
// Kernel A (MFMA + LDS bounce): xp = 2*(x @ W_ih^T + b_ih + b_hh).
// R5 post-mortem: every direct-load variant capped at ~3.5 TB/s because each
// wave load instruction scattered 64x16B sectors across 512-B-strided rows.
// Fix: CONTIGUOUS 1-KB global loads (lane l <- base + l*16) reg-staged into
// an XOR-swizzled LDS tile (phys = L ^ ((row&7)<<4)); MFMA A-fragments then
// come from ds_read_b128 at swizzled addresses (~2-way aliasing = free).
// LDS double-buffer (2x8KB/wave) + 2 reg staging banks = loads 2 tiles ahead.
// W fragments (hi+lo bf16 split) stay resident in 64 VGPRs.
// ---------------------------------------------------------------------------
#define TPW 8   // 16-row tiles per wave

__global__ __launch_bounds__(256, 2) void k_input_proj(
    const float* __restrict__ x, const float* __restrict__ W_ih,
    const float* __restrict__ b_ih, const float* __restrict__ b_hh,
    float* __restrict__ xp)
{
  __shared__ __align__(16) char ldsbuf[4][2][8192];  // [wave][dbuf][8KB tile]
  const int lane = threadIdx.x & 63;
  const int wv   = threadIdx.x >> 6;
  const int gw   = blockIdx.x * 4 + wv;   // global wave id
  const int rr   = lane & 15;   // A-row within tile / C-col
  const int kq   = lane >> 4;   // k-group (0..3), 8 k's each

  // ---- W -> resident B fragments (hi/lo, 2 n-tiles x 4 k-chunks)
  short8v Bhi[2][4], Blo[2][4];
#pragma unroll
  for (int nt = 0; nt < 2; ++nt) {
    const int n = nt * 16 + rr;
    const bool v = (n < HID);
#pragma unroll
    for (int k = 0; k < 4; ++k) {
      float4 wa = {0.f, 0.f, 0.f, 0.f}, wb = {0.f, 0.f, 0.f, 0.f};
      if (v) {
        const float* wp = W_ih + n * NFEAT + k * 32 + kq * 8;
        wa = *reinterpret_cast<const float4*>(wp);
        wb = *reinterpret_cast<const float4*>(wp + 4);
      }
      cvt_hilo(wa, wb, Bhi[nt][k], Blo[nt][k]);
    }
  }

  const float badd0 = b_ih[rr] + b_hh[rr];
  const int   n1    = 16 + rr;
  const float badd1 = (n1 < HID) ? (b_ih[n1] + b_hh[n1]) : 0.0f;

  const int t0  = gw * TPW;
  const int lby = lane * 16;        // byte offset of this lane's 16B in a 1KB seg
  const int lhi = lane >> 5;        // row parity within a 1KB segment

  char* const ldsw = &ldsbuf[wv][0][0];
  // swizzled read bases (logical L = rr*512 + kq*32 (+16); phys = L^((rr&7)<<4))
  const int rdp0 = (rr * 512 + kq * 32)      ^ ((rr & 7) << 4);
  const int rdp1 = (rr * 512 + kq * 32 + 16) ^ ((rr & 7) << 4);

// contiguous 1KB-per-instr global load of one 8KB tile into regs
#define LOADR(STG, T) {                                                        \
    const float4* gp = reinterpret_cast<const float4*>(x + (size_t)(T) * 2048) \
                       + lane;                                                 \
    _Pragma("unroll")                                                          \
    for (int jj = 0; jj < 8; ++jj) STG[jj] = gp[jj * 64]; }

// regs -> swizzled LDS tile (conflict-free b128 writes: XOR permutes granules)
#define WRITEL(BUF, STG) {                                                     \
    char* lb_ = ldsw + (BUF) * 8192;                                           \
    _Pragma("unroll")                                                          \
    for (int jj = 0; jj < 8; ++jj) {                                           \
      const int phys_ = (jj * 1024 + lby) ^ (((2 * jj + lhi) & 7) << 4);       \
      *reinterpret_cast<float4*>(lb_ + phys_) = STG[jj];                       \
    } }

#define COMPSTORE(BUF, T) {                                                    \
    const char* lb_ = ldsw + (BUF) * 8192;                                     \
    f32x4 acc0 = {0.f, 0.f, 0.f, 0.f};                                         \
    f32x4 acc1 = {0.f, 0.f, 0.f, 0.f};                                         \
    _Pragma("unroll")                                                          \
    for (int k = 0; k < 4; ++k) {                                              \
      const float4 ca = *reinterpret_cast<const float4*>(lb_ + rdp0 + k * 128);\
      const float4 cb = *reinterpret_cast<const float4*>(lb_ + rdp1 + k * 128);\
      short8v Ahi, Alo;                                                        \
      cvt_hilo(ca, cb, Ahi, Alo);                                              \
      acc0 = __builtin_amdgcn_mfma_f32_16x16x32_bf16(Ahi, Bhi[0][k], acc0, 0, 0, 0); \
      acc0 = __builtin_amdgcn_mfma_f32_16x16x32_bf16(Ahi, Blo[0][k], acc0, 0, 0, 0); \
      acc0 = __builtin_amdgcn_mfma_f32_16x16x32_bf16(Alo, Bhi[0][k], acc0, 0, 0, 0); \
      acc1 = __builtin_amdgcn_mfma_f32_16x16x32_bf16(Ahi, Bhi[1][k], acc1, 0, 0, 0); \
      acc1 = __builtin_amdgcn_mfma_f32_16x16x32_bf16(Ahi, Blo[1][k], acc1, 0, 0, 0); \
      acc1 = __builtin_amdgcn_mfma_f32_16x16x32_bf16(Alo, Bhi[1][k], acc1, 0, 0, 0); \
    }                                                                          \
    const int R = (T) * 16;                                                    \
    _Pragma("unroll")                                                          \
    for (int reg = 0; reg < 4; ++reg) {                                        \
      float* prow = xp + (size_t)(R + kq * 4 + reg) * HID;                     \
      prow[rr] = 2.0f * (acc0[reg] + badd0);                                   \
      if (n1 < HID) prow[n1] = 2.0f * (acc1[reg] + badd1);                     \
    } }

  float4 stgA[8], stgB[8];   // staging banks: even-parity / odd-parity tiles

  LOADR(stgA, t0);           // tile 0
  WRITEL(0, stgA);           // -> LDS buf 0
  LOADR(stgB, t0 + 1);       // tile 1 in flight during tile-0 compute

#pragma unroll
  for (int tt = 0; tt < TPW; ++tt) {
    const int buf = tt & 1;
    COMPSTORE(buf, t0 + tt);
    if (tt + 1 < TPW) {
      if (buf == 0) { WRITEL(1, stgB); if (tt + 2 < TPW) LOADR(stgA, t0 + tt + 2); }
      else          { WRITEL(0, stgA); if (tt + 2 < TPW) LOADR(stgB, t0 + tt + 2); }
    }
  }
#undef LOADR
#undef WRITEL
#undef COMPSTORE
}

// ---------------------------------------------------------------------------
// Kernel B: 512-step recurrence + final FC (unchanged from R5, passed).
// 1 wave/block, 3 batches/wave, lane j owns h[j] + 2*W_hh row j in VGPRs;
// h exchanged via 1 ds_write + 5 conflict-free broadcast ds_read_b128/step.
// xp arrives pre-scaled by 2, so tanh(s) = (e^{s'}-1)/(e^{s'}+1), s'=2s.
// ---------------------------------------------------------------------------
#define BPW 3   // batches per wave
#define PF  8   // xp prefetch chunk (steps)

__device__ __forceinline__ float tanh_scaled(float sp) {  // sp = 2*s
  sp = fminf(fmaxf(sp, -18.0f), 18.0f);
  const float e = __expf(sp);
  return (e - 1.0f) * __builtin_amdgcn_rcpf(e + 1.0f);
}

__global__ __launch_bounds__(64) void k_rnn_scan(
    const float* __restrict__ xp, const float* __restrict__ W_hh,
    const float* __restrict__ W_fc, const float* __restrict__ b_fc,
    float* __restrict__ out)
{
  __shared__ __align__(16) float hsh[4][HID];  // [group][h]
  const int lane = threadIdx.x;
  const int g = lane / HID;        // 0..3
  const int j = lane - g * HID;    // 0..19
  const int b = blockIdx.x * BPW + g;
  const bool valid = (g < BPW) && (b < BATCH);
  const int beff = valid ? b : 0;

  // W_hh row j -> registers, pre-scaled by 2
  float w[HID];
  {
    const float4* wr = reinterpret_cast<const float4*>(W_hh + j * HID);
#pragma unroll
    for (int qq = 0; qq < HID / 4; ++qq) {
      const float4 v = wr[qq];
      w[qq * 4 + 0] = 2.0f * v.x; w[qq * 4 + 1] = 2.0f * v.y;
      w[qq * 4 + 2] = 2.0f * v.z; w[qq * 4 + 3] = 2.0f * v.w;
    }
  }

  hsh[g][j] = 0.0f;
  __builtin_amdgcn_wave_barrier();

  const float* __restrict__ xl = xp + beff * HID + j;
  const int STRIDE = BATCH * HID;
  const float4* __restrict__ hp = reinterpret_cast<const float4*>(&hsh[g][0]);

  float bufA[PF], bufB[PF];

#define STEPF(XV)                                                              \
  {                                                                            \
    float4 h0 = hp[0], h1 = hp[1], h2 = hp[2], h3 = hp[3], h4 = hp[4];         \
    float a0 = fmaf(w[3], h0.w, fmaf(w[2], h0.z, fmaf(w[1], h0.y, fmaf(w[0], h0.x, (XV))))); \
    float a1 = fmaf(w[7], h1.w, fmaf(w[6], h1.z, fmaf(w[5], h1.y, w[4] * h1.x)));            \
    float a2 = fmaf(w[11], h2.w, fmaf(w[10], h2.z, fmaf(w[9], h2.y, w[8] * h2.x)));          \
    float a3 = fmaf(w[15], h3.w, fmaf(w[14], h3.z, fmaf(w[13], h3.y, w[12] * h3.x)));        \
    float a4 = fmaf(w[19], h4.w, fmaf(w[18], h4.z, fmaf(w[17], h4.y, w[16] * h4.x)));        \
    float s_ = (a0 + a1) + ((a2 + a3) + a4);                                   \
    float hn = tanh_scaled(s_);                                                \
    __builtin_amdgcn_wave_barrier();                                           \
    hsh[g][j] = hn;                                                            \
    __builtin_amdgcn_wave_barrier();                                           \
  }

#pragma unroll
  for (int i = 0; i < PF; ++i) bufA[i] = xl[i * STRIDE];

  for (int c = 0; c < SEQ / PF; c += 2) {
#pragma unroll
    for (int i = 0; i < PF; ++i) bufB[i] = xl[((c + 1) * PF + i) * STRIDE];
#pragma unroll
    for (int i = 0; i < PF; ++i) STEPF(bufA[i]);
    if (c + 2 < SEQ / PF) {
#pragma unroll
      for (int i = 0; i < PF; ++i) bufA[i] = xl[((c + 2) * PF + i) * STRIDE];
    }
#pragma unroll
    for (int i = 0; i < PF; ++i) STEPF(bufB[i]);
  }

  // FC epilogue: out[b][c] = b_fc[c] + sum_k W_fc[c][k] * h_final[k]
  if (valid && j < NCLS) {
    float acc = b_fc[j];
#pragma unroll
    for (int k = 0; k < HID; ++k)
      acc = fmaf(W_fc[j * HID + k], hsh[g][k], acc);
    out[b * NCLS + j] = acc;
  }
#undef STEPF
}

// ---------------------------------------------------------------------------
extern "C" void kernel_launch(void* const* d_in, const int* in_sizes, int n_in,
                              void* d_out, int out_size, void* d_ws, size_t ws_size,
                              hipStream_t stream) {
  const float* x    = (const float*)d_in[0];
  const float* W_ih = (const float*)d_in[1];
  const float* W_hh = (const float*)d_in[2];
  const float* b_ih = (const float*)d_in[3];
  const float* b_hh = (const float*)d_in[4];
  const float* W_fc = (const float*)d_in[5];
  const float* b_fc = (const float*)d_in[6];
  float* out = (float*)d_out;

  float* xp = (float*)d_ws;  // SEQ*BATCH*HID floats = 41.9 MB

  // 32768 tiles / (1024 blocks * 4 waves) = 8 tiles per wave
  k_input_proj<<<1024, 256, 0, stream>>>(x, W_ih, b_ih, b_hh, xp);

  const int nblk = (BATCH + BPW - 1) / BPW;  // 342
  k_rnn_scan<<<nblk, 64, 0, stream>>>(xp, W_hh, W_fc, b_fc, out);
}